// Round 3
// baseline (323.846 us; speedup 1.0000x reference)
//
#include <hip/hip_runtime.h>
#include <hip/hip_bf16.h>

// Swin window attention, fully fused. 1 block = 1 window (4096 blocks),
// 512 threads = 8 waves = 4 heads x 2 q-halves.
// N=49 tokens (padded to 64), DIM=128, H=4, HD=32.

typedef short bf16x8 __attribute__((ext_vector_type(8)));
typedef float f32x4  __attribute__((ext_vector_type(4)));

#define MFMA16(a, b, c) __builtin_amdgcn_mfma_f32_16x16x32_bf16((a), (b), (c), 0, 0, 0)

union bf8u { bf16x8 v; unsigned u[4]; };

// packed f32x2 -> bf16x2 (RNE), 1 VALU instr
static __device__ __forceinline__ unsigned pk2(float a, float b) {
  unsigned r;
  asm("v_cvt_pk_bf16_f32 %0, %1, %2" : "=v"(r) : "v"(a), "v"(b));
  return r;
}

static __device__ __forceinline__ unsigned short f2b(float f) {
  unsigned u = __float_as_uint(f);
  u = u + 0x7FFFu + ((u >> 16) & 1u);   // RNE
  return (unsigned short)(u >> 16);
}

// ---------------- prep ----------------
// ws layout (bytes):
//   [0,      98304)   Wt  : bf16 [384][128], Wt[c][k] = qkv_w[k][c]
//   [98304, 131072)   Pt  : bf16 [128][128], Pt[c][k] = proj_w[k][c]
//   [131072,1179648)  BM2 : f32  [64][mt(4)][nt(4)][lane(64)][r(4)]
//                      = bias[q][k]+mask[w][q][k], q=mt*16+lc, k=nt*16+lq*4+r
//                      (pad q/k>=49 -> -1e30); fragment-order => coalesced float4
__global__ void prep_kernel(const float* __restrict__ qkv_w,
                            const float* __restrict__ proj_w,
                            const float* __restrict__ bias_table,
                            const int* __restrict__ rel_index,
                            const float* __restrict__ mask,
                            unsigned short* __restrict__ Wt,
                            unsigned short* __restrict__ Pt,
                            float* __restrict__ BM2) {
  int idx = blockIdx.x * 256 + threadIdx.x;
  if (idx < 384 * 128) {
    int c = idx >> 7, k = idx & 127;
    Wt[idx] = f2b(qkv_w[k * 384 + c]);
  }
  if (idx < 128 * 128) {
    int c = idx >> 7, k = idx & 127;
    Pt[idx] = f2b(proj_w[k * 128 + c]);
  }
  if (idx < 64 * 4096) {
    int w = idx >> 12, rem = idx & 4095;
    int mt = rem >> 10, nt = (rem >> 8) & 3, ln = (rem >> 2) & 63, r = rem & 3;
    int lq = ln >> 4, lc = ln & 15;
    int q = mt * 16 + lc, k = nt * 16 + lq * 4 + r;
    float v = -1e30f;
    if (q < 49 && k < 49)
      v = bias_table[rel_index[q * 49 + k]] + mask[(w * 49 + q) * 49 + k];
    BM2[idx] = v;
  }
}

// ---------------- fused kernel ----------------
__global__ __launch_bounds__(512, 6)
void winattn_fused(const float* __restrict__ x,
                   const float* __restrict__ qkv_b,
                   const float* __restrict__ proj_b,
                   const unsigned short* __restrict__ Wt,
                   const unsigned short* __restrict__ Pt,
                   const float* __restrict__ BM2,
                   float* __restrict__ out) {
  // 48 KB LDS (ushort units):
  //  [0,     8192) : Vt bf16[128][64]  -> Os bf16[64][128] (after B2)
  //  [8192, 16384) : Q  bf16[64][128]  -> P waves 0-3 (4x2048 ushorts)
  //  [16384,24576) : K  bf16[64][128]  -> P waves 4-7
  // Row-major tiles swizzled: ushort_idx ^= (row&7)<<3.
  __shared__ unsigned short sh[24576];

  const int b    = blockIdx.x;
  const int tid  = threadIdx.x;
  const int w    = tid >> 6;
  const int lane = tid & 63;
  const int lq   = lane >> 4;
  const int lc   = lane & 15;
  const int h    = w >> 1;      // head (attention phases)
  const int qh   = w & 1;       // q-half (attention phases)
  const int p    = w >> 1;      // colgroup pair (QKV phase)
  const int mt0  = (w & 1) * 2; // token-tile half (QKV phase)

  const f32x4 vzero = {0.f, 0.f, 0.f, 0.f};
  const int QBASE = 8192, KBASE = 16384;

  // ---- P2: QKV. Wave computes colgroups {p, p+4, p+8, p+12, p+16, p+20}
  //          for token tiles {mt0, mt0+1}.
  {
    const float* xb = x + (size_t)b * 6272;
    bf8u xf[2][4];   // [m][kt]
#pragma unroll
    for (int m = 0; m < 2; ++m) {
      int t = (mt0 + m) * 16 + lc;
      bool valid = (t < 49);
#pragma unroll
      for (int kt = 0; kt < 4; ++kt) {
        if (valid) {
          const float* ptr = xb + t * 128 + kt * 32 + lq * 8;
          float4 a0 = *reinterpret_cast<const float4*>(ptr);
          float4 a1 = *reinterpret_cast<const float4*>(ptr + 4);
          xf[m][kt].u[0] = pk2(a0.x, a0.y);
          xf[m][kt].u[1] = pk2(a0.z, a0.w);
          xf[m][kt].u[2] = pk2(a1.x, a1.y);
          xf[m][kt].u[3] = pk2(a1.z, a1.w);
        } else {
          xf[m][kt].u[0] = 0; xf[m][kt].u[1] = 0;
          xf[m][kt].u[2] = 0; xf[m][kt].u[3] = 0;
        }
      }
    }
#pragma unroll
    for (int j = 0; j < 6; ++j) {
      int cg = p + j * 4;                 // 0..23
      bf16x8 wtf[4];
#pragma unroll
      for (int kt = 0; kt < 4; ++kt)
        wtf[kt] = *reinterpret_cast<const bf16x8*>(
            &Wt[(cg * 16 + lc) * 128 + kt * 32 + lq * 8]);
      if (j < 4) {
        // Q/K, swapped orientation: C[c][t], lane holds 4 consecutive channels
        float4 b4 = *reinterpret_cast<const float4*>(&qkv_b[cg * 16 + lq * 4]);
        float scale = (j < 2) ? 0.17677669529663687f : 1.0f;
        int base = (j < 2) ? QBASE : KBASE;
        int cp = ((j < 2) ? cg : (cg - 8)) * 16 + lq * 4;
#pragma unroll
        for (int m = 0; m < 2; ++m) {
          f32x4 acc = vzero;
#pragma unroll
          for (int kt = 0; kt < 4; ++kt)
            acc = MFMA16(wtf[kt], xf[m][kt].v, acc);
          int t = (mt0 + m) * 16 + lc;
          uint2 wv;
          wv.x = pk2((acc[0] + b4.x) * scale, (acc[1] + b4.y) * scale);
          wv.y = pk2((acc[2] + b4.z) * scale, (acc[3] + b4.w) * scale);
          *reinterpret_cast<uint2*>(&sh[base + t * 128 + (cp ^ ((t & 7) << 3))]) = wv;
        }
      } else {
        // V, normal orientation: C[t][c], lane holds 4 consecutive tokens
        int vc = (cg - 16) * 16 + lc;     // V channel = Vt row
        float bias = qkv_b[256 + vc];
#pragma unroll
        for (int m = 0; m < 2; ++m) {
          f32x4 acc = vzero;
#pragma unroll
          for (int kt = 0; kt < 4; ++kt)
            acc = MFMA16(xf[m][kt].v, wtf[kt], acc);
          int t0 = (mt0 + m) * 16 + lq * 4;
          uint2 wv;
          wv.x = pk2(acc[0] + bias, acc[1] + bias);
          wv.y = pk2(acc[2] + bias, acc[3] + bias);
          *reinterpret_cast<uint2*>(&sh[vc * 64 + (t0 ^ ((vc & 7) << 3))]) = wv;
        }
      }
    }
  }
  __syncthreads();   // B0: Q/K/Vt complete

  // ---- P3: S^T = K.Q (swapped). Wave = (head h, q-half qh). 8 MFMA.
  f32x4 s[4][2];   // [nt(k)][qb(q)]
  {
    int d0 = h * 32 + lq * 8;
    bf16x8 qf[2], kf[4];
#pragma unroll
    for (int qb = 0; qb < 2; ++qb) {
      int t = qh * 32 + qb * 16 + lc;
      qf[qb] = *reinterpret_cast<const bf16x8*>(
          &sh[QBASE + t * 128 + (d0 ^ ((t & 7) << 3))]);
    }
#pragma unroll
    for (int nt = 0; nt < 4; ++nt) {
      int t = nt * 16 + lc;
      kf[nt] = *reinterpret_cast<const bf16x8*>(
          &sh[KBASE + t * 128 + (d0 ^ ((t & 7) << 3))]);
    }
#pragma unroll
    for (int nt = 0; nt < 4; ++nt)
#pragma unroll
      for (int qb = 0; qb < 2; ++qb)
        s[nt][qb] = MFMA16(kf[nt], qf[qb], vzero);
  }
  __syncthreads();   // B1: Q/K reads done -> regions reusable for P

  // ---- P4: softmax (BM2 fragments from L2), unnormalized P -> own 4K buffer
  float inv_[2];
  const int pbase = 8192 + w * 2048;   // P_w[32 qloc][64 k]
  {
    const float* bm = BM2 + ((size_t)(b & 63) << 12);
#pragma unroll
    for (int qb = 0; qb < 2; ++qb) {
      int mt_g = qh * 2 + qb;
      float4 bmv[4];
#pragma unroll
      for (int nt = 0; nt < 4; ++nt)
        bmv[nt] = *reinterpret_cast<const float4*>(&bm[(mt_g * 4 + nt) * 256 + lane * 4]);
      float v[4][4];
#pragma unroll
      for (int nt = 0; nt < 4; ++nt) {
        v[nt][0] = s[nt][qb][0] + bmv[nt].x;
        v[nt][1] = s[nt][qb][1] + bmv[nt].y;
        v[nt][2] = s[nt][qb][2] + bmv[nt].z;
        v[nt][3] = s[nt][qb][3] + bmv[nt].w;
      }
      float mx = v[0][0];
#pragma unroll
      for (int nt = 0; nt < 4; ++nt)
#pragma unroll
        for (int r = 0; r < 4; ++r) mx = fmaxf(mx, v[nt][r]);
      mx = fmaxf(mx, __shfl_xor(mx, 16, 64));
      mx = fmaxf(mx, __shfl_xor(mx, 32, 64));
      float e[4][4], sum = 0.f;
#pragma unroll
      for (int nt = 0; nt < 4; ++nt)
#pragma unroll
        for (int r = 0; r < 4; ++r) { e[nt][r] = __expf(v[nt][r] - mx); sum += e[nt][r]; }
      sum += __shfl_xor(sum, 16, 64);
      sum += __shfl_xor(sum, 32, 64);
      inv_[qb] = 1.0f / sum;
      int qloc = qb * 16 + lc;
#pragma unroll
      for (int nt = 0; nt < 4; ++nt) {
        int k0 = nt * 16 + lq * 4;
        uint2 wv;
        wv.x = pk2(e[nt][0], e[nt][1]);
        wv.y = pk2(e[nt][2], e[nt][3]);
        *reinterpret_cast<uint2*>(&sh[pbase + qloc * 64 + (k0 ^ ((qloc & 7) << 3))]) = wv;
      }
    }
  }
  // no barrier: wave reads only its own P buffer (same-wave LDS is in-order)

  // ---- P5: O^T = Vt.P (swapped). 8 MFMA.
  f32x4 oacc[2][2];  // [db][qb]
  {
#pragma unroll
    for (int db = 0; db < 2; ++db)
#pragma unroll
      for (int qb = 0; qb < 2; ++qb) oacc[db][qb] = vzero;
#pragma unroll
    for (int kt = 0; kt < 2; ++kt) {
      int k0 = kt * 32 + lq * 8;
      bf16x8 vtf[2], pf[2];
#pragma unroll
      for (int db = 0; db < 2; ++db) {
        int vr = h * 32 + db * 16 + lc;
        vtf[db] = *reinterpret_cast<const bf16x8*>(
            &sh[vr * 64 + (k0 ^ ((vr & 7) << 3))]);
      }
#pragma unroll
      for (int qb = 0; qb < 2; ++qb) {
        int qloc = qb * 16 + lc;
        pf[qb] = *reinterpret_cast<const bf16x8*>(
            &sh[pbase + qloc * 64 + (k0 ^ ((qloc & 7) << 3))]);
      }
#pragma unroll
      for (int db = 0; db < 2; ++db)
#pragma unroll
        for (int qb = 0; qb < 2; ++qb)
          oacc[db][qb] = MFMA16(vtf[db], pf[qb], oacc[db][qb]);
    }
  }
  __syncthreads();   // B2: all Vt/P reads done -> region 0 reusable for Os

  // ---- Os write: Os[t][d], normalized
  {
#pragma unroll
    for (int db = 0; db < 2; ++db)
#pragma unroll
      for (int qb = 0; qb < 2; ++qb) {
        int t = qh * 32 + qb * 16 + lc;
        int dp = h * 32 + db * 16 + lq * 4;
        float iv = inv_[qb];
        uint2 wv;
        wv.x = pk2(oacc[db][qb][0] * iv, oacc[db][qb][1] * iv);
        wv.y = pk2(oacc[db][qb][2] * iv, oacc[db][qb][3] * iv);
        *reinterpret_cast<uint2*>(&sh[t * 128 + (dp ^ ((t & 7) << 3))]) = wv;
      }
  }
  __syncthreads();   // B3: Os complete

  // ---- P6: out^T = Pt.Os (swapped). Wave = out colgroup w. 16 MFMA.
  {
    bf16x8 ptf[4];
#pragma unroll
    for (int kt = 0; kt < 4; ++kt)
      ptf[kt] = *reinterpret_cast<const bf16x8*>(
          &Pt[(w * 16 + lc) * 128 + kt * 32 + lq * 8]);
    f32x4 acc[4];
#pragma unroll
    for (int tb = 0; tb < 4; ++tb) acc[tb] = vzero;
#pragma unroll
    for (int kt = 0; kt < 4; ++kt) {
      int d0 = kt * 32 + lq * 8;
#pragma unroll
      for (int tb = 0; tb < 4; ++tb) {
        int t = tb * 16 + lc;
        bf16x8 osf = *reinterpret_cast<const bf16x8*>(
            &sh[t * 128 + (d0 ^ ((t & 7) << 3))]);
        acc[tb] = MFMA16(ptf[kt], osf, acc[tb]);
      }
    }
    float* ob = out + (size_t)b * 6272;
    float4 pb4 = *reinterpret_cast<const float4*>(&proj_b[w * 16 + lq * 4]);
#pragma unroll
    for (int tb = 0; tb < 4; ++tb) {
      int t = tb * 16 + lc;
      if (t < 49) {
        float4 o4;
        o4.x = acc[tb][0] + pb4.x;
        o4.y = acc[tb][1] + pb4.y;
        o4.z = acc[tb][2] + pb4.z;
        o4.w = acc[tb][3] + pb4.w;
        *reinterpret_cast<float4*>(&ob[t * 128 + w * 16 + lq * 4]) = o4;
      }
    }
  }
}

extern "C" void kernel_launch(void* const* d_in, const int* in_sizes, int n_in,
                              void* d_out, int out_size, void* d_ws, size_t ws_size,
                              hipStream_t stream) {
  const float* x         = (const float*)d_in[0];
  const float* mask      = (const float*)d_in[1];
  const float* qkv_w     = (const float*)d_in[2];
  const float* qkv_b     = (const float*)d_in[3];
  const float* proj_w    = (const float*)d_in[4];
  const float* proj_b    = (const float*)d_in[5];
  const float* bias_tab  = (const float*)d_in[6];
  const int*   rel_index = (const int*)d_in[7];
  float* out = (float*)d_out;

  unsigned short* Wt  = (unsigned short*)d_ws;                      // 384*128 bf16
  unsigned short* Pt  = (unsigned short*)((char*)d_ws + 98304);     // 128*128 bf16
  float*          BM2 = (float*)((char*)d_ws + 131072);             // 64*4096 f32

  hipLaunchKernelGGL(prep_kernel, dim3(1024), dim3(256), 0, stream,
                     qkv_w, proj_w, bias_tab, rel_index, mask, Wt, Pt, BM2);
  hipLaunchKernelGGL(winattn_fused, dim3(4096), dim3(512), 0, stream,
                     x, qkv_b, proj_b, Wt, Pt, BM2, out);
}

// Round 5
// 290.520 us; speedup vs baseline: 1.1147x; 1.1147x over previous
//
#include <hip/hip_runtime.h>
#include <hip/hip_bf16.h>

// Swin window attention, fully fused. 1 block = 1 window (4096 blocks),
// 256 threads = 4 waves; wave = one head END-TO-END (only proj mixes heads).
// Barriers: 2. Per-wave private LDS regions; same-wave LDS needs no barrier.
// N=49 tokens (padded 64), DIM=128, H=4, HD=32.

typedef short bf16x8 __attribute__((ext_vector_type(8)));
typedef float f32x4  __attribute__((ext_vector_type(4)));

#define MFMA16(a, b, c) __builtin_amdgcn_mfma_f32_16x16x32_bf16((a), (b), (c), 0, 0, 0)

union bf8u { bf16x8 v; unsigned u[4]; };

// packed f32x2 -> bf16x2 (RNE), 1 VALU instr
static __device__ __forceinline__ unsigned pk2(float a, float b) {
  unsigned r;
  asm("v_cvt_pk_bf16_f32 %0, %1, %2" : "=v"(r) : "v"(a), "v"(b));
  return r;
}

static __device__ __forceinline__ unsigned short f2b(float f) {
  unsigned u = __float_as_uint(f);
  u = u + 0x7FFFu + ((u >> 16) & 1u);   // RNE
  return (unsigned short)(u >> 16);
}

// ---------------- prep (unchanged, proven) ----------------
// ws layout (bytes):
//   [0,      98304)   Wt  : bf16 [384][128], Wt[c][k] = qkv_w[k][c]
//   [98304, 131072)   Pt  : bf16 [128][128], Pt[c][k] = proj_w[k][c]
//   [131072,1179648)  BM2 : f32  [64][mt(4)][nt(4)][lane(64)][r(4)]
//                      = bias[q][k]+mask[w][q][k], q=mt*16+lc, k=nt*16+lq*4+r
//                      (pad q/k>=49 -> -1e30); fragment-order => coalesced float4
__global__ void prep_kernel(const float* __restrict__ qkv_w,
                            const float* __restrict__ proj_w,
                            const float* __restrict__ bias_table,
                            const int* __restrict__ rel_index,
                            const float* __restrict__ mask,
                            unsigned short* __restrict__ Wt,
                            unsigned short* __restrict__ Pt,
                            float* __restrict__ BM2) {
  int idx = blockIdx.x * 256 + threadIdx.x;
  if (idx < 384 * 128) {
    int c = idx >> 7, k = idx & 127;
    Wt[idx] = f2b(qkv_w[k * 384 + c]);
  }
  if (idx < 128 * 128) {
    int c = idx >> 7, k = idx & 127;
    Pt[idx] = f2b(proj_w[k * 128 + c]);
  }
  if (idx < 64 * 4096) {
    int w = idx >> 12, rem = idx & 4095;
    int mt = rem >> 10, nt = (rem >> 8) & 3, ln = (rem >> 2) & 63, r = rem & 3;
    int lq = ln >> 4, lc = ln & 15;
    int q = mt * 16 + lc, k = nt * 16 + lq * 4 + r;
    float v = -1e30f;
    if (q < 49 && k < 49)
      v = bias_table[rel_index[q * 49 + k]] + mask[(w * 49 + q) * 49 + k];
    BM2[idx] = v;
  }
}

// ---------------- fused kernel ----------------
__global__ __launch_bounds__(256, 3)
void winattn_fused(const float* __restrict__ x,
                   const float* __restrict__ qkv_b,
                   const float* __restrict__ proj_b,
                   const unsigned short* __restrict__ Wt,
                   const unsigned short* __restrict__ Pt,
                   const float* __restrict__ BM2,
                   float* __restrict__ out) {
  // 48 KB LDS, byte layout. Wave w private block at PB = w*12288:
  //   Q_h [PB      , PB+4096) : [64 t][32 d]  64B rows, 16B-granule ^ (t&3)
  //   K_h [PB+4096 , PB+8192) : same
  //   Vt_h[PB+8192 , PB+12288): [32 d][64 t] 128B rows, 16B-granule ^ (d&7)
  //   P_h (after S reads)     : [PB, PB+8192) [64 q][64 k] 128B rows, ^ (q&7)
  //   Os  (after barrier B1)  : bytes [0,16384) [64 t][128 d] 256B rows, ^ (t&7)
  __shared__ unsigned short sh[24576];
  char* shb = (char*)sh;

  const int b    = blockIdx.x;
  const int tid  = threadIdx.x;
  const int w    = tid >> 6;    // wave = head
  const int lane = tid & 63;
  const int lq   = lane >> 4;
  const int lc   = lane & 15;

  const f32x4 vzero = {0.f, 0.f, 0.f, 0.f};
  char* Qb = shb + w * 12288;
  char* Kb = Qb + 4096;
  char* Vb = Qb + 8192;
  char* Pb = Qb;                // P overlays Q+K after S frag reads

  // ---- X fragments from global (t = mt*16+lc, d = kt*32+lq*8)
  bf8u xf[4][4];   // [kt][mt]
  {
    const float* xb = x + (size_t)b * 6272;
#pragma unroll
    for (int mt = 0; mt < 4; ++mt) {
      int t = mt * 16 + lc;
      bool valid = (t < 49);
#pragma unroll
      for (int kt = 0; kt < 4; ++kt) {
        if (valid) {
          const float* p = xb + t * 128 + kt * 32 + lq * 8;
          float4 a0 = *reinterpret_cast<const float4*>(p);
          float4 a1 = *reinterpret_cast<const float4*>(p + 4);
          xf[kt][mt].u[0] = pk2(a0.x, a0.y);
          xf[kt][mt].u[1] = pk2(a0.z, a0.w);
          xf[kt][mt].u[2] = pk2(a1.x, a1.y);
          xf[kt][mt].u[3] = pk2(a1.z, a1.w);
        } else {
          xf[kt][mt].u[0] = 0; xf[kt][mt].u[1] = 0;
          xf[kt][mt].u[2] = 0; xf[kt][mt].u[3] = 0;
        }
      }
    }
  }

  // ---- QKV for own head: cgs {Q: 2w,2w+1}, {K: 8+2w,+1}, {V: 16+2w,+1}
  {
#pragma unroll
    for (int j = 0; j < 6; ++j) {
      int part = j >> 1;               // 0=Q 1=K 2=V
      int half = j & 1;
      int cg = part * 8 + w * 2 + half;
      bf16x8 wtf[4];
#pragma unroll
      for (int kt = 0; kt < 4; ++kt)
        wtf[kt] = *reinterpret_cast<const bf16x8*>(
            &Wt[(cg * 16 + lc) * 128 + kt * 32 + lq * 8]);
      if (part < 2) {
        // swapped: C[c][t], lane holds 4 consecutive channels, t = lc
        float4 b4 = *reinterpret_cast<const float4*>(&qkv_b[cg * 16 + lq * 4]);
        float scale = (part == 0) ? 0.17677669529663687f : 1.0f;
        char* dst = (part == 0) ? Qb : Kb;
#pragma unroll
        for (int mt = 0; mt < 4; ++mt) {
          f32x4 acc = vzero;
#pragma unroll
          for (int kt = 0; kt < 4; ++kt)
            acc = MFMA16(wtf[kt], xf[kt][mt].v, acc);
          int t = mt * 16 + lc;
          int g = (half * 2 + (lq >> 1)) ^ (t & 3);
          uint2 wv;
          wv.x = pk2((acc[0] + b4.x) * scale, (acc[1] + b4.y) * scale);
          wv.y = pk2((acc[2] + b4.z) * scale, (acc[3] + b4.w) * scale);
          *reinterpret_cast<uint2*>(dst + t * 64 + g * 16 + (lq & 1) * 8) = wv;
        }
      } else {
        // normal: C[t][c], lane holds 4 consecutive tokens, d_local = half*16+lc
        int d = half * 16 + lc;        // 0..31 within head
        float bias = qkv_b[256 + w * 32 + d];
#pragma unroll
        for (int mt = 0; mt < 4; ++mt) {
          f32x4 acc = vzero;
#pragma unroll
          for (int kt = 0; kt < 4; ++kt)
            acc = MFMA16(xf[kt][mt].v, wtf[kt], acc);
          int g = (mt * 2 + (lq >> 1)) ^ (d & 7);
          uint2 wv;
          wv.x = pk2(acc[0] + bias, acc[1] + bias);
          wv.y = pk2(acc[2] + bias, acc[3] + bias);
          *reinterpret_cast<uint2*>(Vb + d * 128 + g * 16 + (lq & 1) * 8) = wv;
        }
      }
    }
  }
  // no barrier: everything below reads only this wave's own regions

  // ---- S^T = K.Q (swapped). Lane: k = nt*16+lq*4+r, q = mt*16+lc.
  f32x4 s[4][4];   // [nt][mt]
  {
    bf16x8 qf[4], kf[4];
#pragma unroll
    for (int mt = 0; mt < 4; ++mt) {
      int t = mt * 16 + lc;
      qf[mt] = *reinterpret_cast<const bf16x8*>(Qb + t * 64 + ((lq ^ (t & 3)) * 16));
    }
#pragma unroll
    for (int nt = 0; nt < 4; ++nt) {
      int t = nt * 16 + lc;
      kf[nt] = *reinterpret_cast<const bf16x8*>(Kb + t * 64 + ((lq ^ (t & 3)) * 16));
    }
#pragma unroll
    for (int nt = 0; nt < 4; ++nt)
#pragma unroll
      for (int mt = 0; mt < 4; ++mt)
        s[nt][mt] = MFMA16(kf[nt], qf[mt], vzero);
  }

  // ---- softmax (BM2 pipelined 1 mt-tile ahead), unnormalized P -> P_h
  float inv_[4];
  {
    const float* bm = BM2 + ((size_t)(b & 63) << 12);
    float4 bmv[4];
#pragma unroll
    for (int nt = 0; nt < 4; ++nt)
      bmv[nt] = *reinterpret_cast<const float4*>(&bm[nt * 256 + lane * 4]);
#pragma unroll
    for (int mt = 0; mt < 4; ++mt) {
      float4 cur[4];
#pragma unroll
      for (int nt = 0; nt < 4; ++nt) cur[nt] = bmv[nt];
      if (mt < 3) {
#pragma unroll
        for (int nt = 0; nt < 4; ++nt)
          bmv[nt] = *reinterpret_cast<const float4*>(
              &bm[((mt + 1) * 4 + nt) * 256 + lane * 4]);
      }
      float v[4][4];
#pragma unroll
      for (int nt = 0; nt < 4; ++nt) {
        v[nt][0] = s[nt][mt][0] + cur[nt].x;
        v[nt][1] = s[nt][mt][1] + cur[nt].y;
        v[nt][2] = s[nt][mt][2] + cur[nt].z;
        v[nt][3] = s[nt][mt][3] + cur[nt].w;
      }
      float mx = v[0][0];
#pragma unroll
      for (int nt = 0; nt < 4; ++nt)
#pragma unroll
        for (int r = 0; r < 4; ++r) mx = fmaxf(mx, v[nt][r]);
      mx = fmaxf(mx, __shfl_xor(mx, 16, 64));
      mx = fmaxf(mx, __shfl_xor(mx, 32, 64));
      float e[4][4], sum = 0.f;
#pragma unroll
      for (int nt = 0; nt < 4; ++nt)
#pragma unroll
        for (int r = 0; r < 4; ++r) { e[nt][r] = __expf(v[nt][r] - mx); sum += e[nt][r]; }
      sum += __shfl_xor(sum, 16, 64);
      sum += __shfl_xor(sum, 32, 64);
      inv_[mt] = 1.0f / sum;
      int q = mt * 16 + lc;
#pragma unroll
      for (int nt = 0; nt < 4; ++nt) {
        int g = (nt * 2 + (lq >> 1)) ^ (q & 7);
        uint2 wv;
        wv.x = pk2(e[nt][0], e[nt][1]);
        wv.y = pk2(e[nt][2], e[nt][3]);
        *reinterpret_cast<uint2*>(Pb + q * 128 + g * 16 + (lq & 1) * 8) = wv;
      }
    }
  }

  // ---- O^T = Vt.P (swapped). Lane: d 4-consec rows, q col = lc.
  f32x4 oacc[2][4];  // [db][qb]
  {
#pragma unroll
    for (int db = 0; db < 2; ++db)
#pragma unroll
      for (int qb = 0; qb < 4; ++qb) oacc[db][qb] = vzero;
#pragma unroll
    for (int kt = 0; kt < 2; ++kt) {
      bf16x8 vtf[2], pf[4];
#pragma unroll
      for (int db = 0; db < 2; ++db) {
        int d = db * 16 + lc;
        vtf[db] = *reinterpret_cast<const bf16x8*>(
            Vb + d * 128 + (((kt * 4 + lq) ^ (d & 7)) * 16));
      }
#pragma unroll
      for (int qb = 0; qb < 4; ++qb) {
        int q = qb * 16 + lc;
        pf[qb] = *reinterpret_cast<const bf16x8*>(
            Pb + q * 128 + (((kt * 4 + lq) ^ (q & 7)) * 16));
      }
#pragma unroll
      for (int db = 0; db < 2; ++db)
#pragma unroll
        for (int qb = 0; qb < 4; ++qb)
          oacc[db][qb] = MFMA16(vtf[db], pf[qb], oacc[db][qb]);
    }
  }
  __syncthreads();   // B1: all waves done with private regions -> Os may alias

  // ---- Os[t][d] write (normalized), bytes [0,16384)
  {
#pragma unroll
    for (int db = 0; db < 2; ++db)
#pragma unroll
      for (int qb = 0; qb < 4; ++qb) {
        int t = qb * 16 + lc;
        int dp = w * 32 + db * 16 + lq * 4;
        float iv = inv_[qb];
        uint2 wv;
        wv.x = pk2(oacc[db][qb][0] * iv, oacc[db][qb][1] * iv);
        wv.y = pk2(oacc[db][qb][2] * iv, oacc[db][qb][3] * iv);
        *reinterpret_cast<uint2*>(&sh[t * 128 + (dp ^ ((t & 7) << 3))]) = wv;
      }
  }
  __syncthreads();   // B2: Os complete

  // ---- proj: out^T = Pt.Os (swapped). Wave handles out cols w*32..w*32+31.
  {
    float* ob = out + (size_t)b * 6272;
#pragma unroll
    for (int i = 0; i < 2; ++i) {
      int cb = w * 2 + i;
      bf16x8 ptf[4];
#pragma unroll
      for (int kt = 0; kt < 4; ++kt)
        ptf[kt] = *reinterpret_cast<const bf16x8*>(
            &Pt[(cb * 16 + lc) * 128 + kt * 32 + lq * 8]);
      f32x4 acc[4];
#pragma unroll
      for (int tb = 0; tb < 4; ++tb) acc[tb] = vzero;
#pragma unroll
      for (int kt = 0; kt < 4; ++kt) {
        int d0 = kt * 32 + lq * 8;
#pragma unroll
        for (int tb = 0; tb < 4; ++tb) {
          int t = tb * 16 + lc;
          bf16x8 osf = *reinterpret_cast<const bf16x8*>(
              &sh[t * 128 + (d0 ^ ((t & 7) << 3))]);
          acc[tb] = MFMA16(ptf[kt], osf, acc[tb]);
        }
      }
      float4 pb4 = *reinterpret_cast<const float4*>(&proj_b[cb * 16 + lq * 4]);
#pragma unroll
      for (int tb = 0; tb < 4; ++tb) {
        int t = tb * 16 + lc;
        if (t < 49) {
          float4 o4;
          o4.x = acc[tb][0] + pb4.x;
          o4.y = acc[tb][1] + pb4.y;
          o4.z = acc[tb][2] + pb4.z;
          o4.w = acc[tb][3] + pb4.w;
          *reinterpret_cast<float4*>(&ob[t * 128 + cb * 16 + lq * 4]) = o4;
        }
      }
    }
  }
}

extern "C" void kernel_launch(void* const* d_in, const int* in_sizes, int n_in,
                              void* d_out, int out_size, void* d_ws, size_t ws_size,
                              hipStream_t stream) {
  const float* x         = (const float*)d_in[0];
  const float* mask      = (const float*)d_in[1];
  const float* qkv_w     = (const float*)d_in[2];
  const float* qkv_b     = (const float*)d_in[3];
  const float* proj_w    = (const float*)d_in[4];
  const float* proj_b    = (const float*)d_in[5];
  const float* bias_tab  = (const float*)d_in[6];
  const int*   rel_index = (const int*)d_in[7];
  float* out = (float*)d_out;

  unsigned short* Wt  = (unsigned short*)d_ws;                      // 384*128 bf16
  unsigned short* Pt  = (unsigned short*)((char*)d_ws + 98304);     // 128*128 bf16
  float*          BM2 = (float*)((char*)d_ws + 131072);             // 64*4096 f32

  hipLaunchKernelGGL(prep_kernel, dim3(1024), dim3(256), 0, stream,
                     qkv_w, proj_w, bias_tab, rel_index, mask, Wt, Pt, BM2);
  hipLaunchKernelGGL(winattn_fused, dim3(4096), dim3(256), 0, stream,
                     x, qkv_b, proj_b, Wt, Pt, BM2, out);
}